// Round 2
// baseline (3366.988 us; speedup 1.0000x reference)
//
#include <hip/hip_runtime.h>
#include <math.h>

// Problem constants (from reference)
#define NG   1024        // graphs (blocks)
#define NP   256         // nodes per graph
#define EPG  4096        // edges per graph
#define ETOT 4194304     // total edges
#define FIN  7
#define HD   64
#define KC   50
#define SST  52          // padded row stride for S / AS (16B-aligned rows, pads = 0)
#define NTH  1024
#define NWAVE 16

__global__ void zero_ws(float* ws) {
    if (threadIdx.x < 2) ws[threadIdx.x] = 0.f;
}

__global__ void finalize_k(const float* __restrict__ ws, float* __restrict__ out) {
    if (threadIdx.x == 0) {
        float link = sqrtf(fmaxf(ws[0], 0.f)) / 67108864.0f;  // / A.size = 1024*256*256
        float ent  = -ws[1] / 262144.0f;                      // / N
        out[2048] = link + ent;
    }
}

__device__ __forceinline__ float blockReduce(float v, float* red) {
    __syncthreads();   // protect red from previous use
    #pragma unroll
    for (int o = 32; o > 0; o >>= 1) v += __shfl_down(v, o);
    if ((threadIdx.x & 63) == 0) red[threadIdx.x >> 6] = v;
    __syncthreads();
    float r = (threadIdx.x < NWAVE) ? red[threadIdx.x] : 0.f;
    #pragma unroll
    for (int o = NWAVE / 2; o > 0; o >>= 1) r += __shfl_down(r, o);
    return r;   // valid on thread 0
}

// One workgroup per graph. 16 waves, ~150 KB LDS -> 1 block/CU, 4 waves/SIMD.
__launch_bounds__(NTH, 4)
__global__ void graph_k(
    const float* __restrict__ x,
    const float* __restrict__ W1a, const float* __restrict__ b1a,
    const float* __restrict__ W1b, const float* __restrict__ b1b,
    const float* __restrict__ Wp,  const float* __restrict__ bp,
    const float* __restrict__ W2a, const float* __restrict__ b2a,
    const float* __restrict__ W2b, const float* __restrict__ b2b,
    const float* __restrict__ Wl,  const float* __restrict__ bl,
    const int* __restrict__ esrc,  const int* __restrict__ edst,
    float* __restrict__ out, float* __restrict__ ws)
{
    // u1: A-count chunks -> t1/h tile (in-place) -> AS (stride 52)
    __shared__ __align__(16) union { unsigned int cnt[16384]; float f[16384]; } u1;
    // u2: x|agg -> S (stride 52) -> h2 | t
    __shared__ __align__(16) float u2f[NP * SST];
    __shared__ __align__(16) float PT[HD * KC];      // xp transposed: PT[d][k]
    __shared__ __align__(16) float ApBuf[KC * KC];   // G, then Ap
    __shared__ __align__(16) unsigned short cells[EPG];
    __shared__ float red[NWAVE];

    const int g = blockIdx.x, tid = threadIdx.x;
    const int lane = tid & 63, wid = tid >> 6;
    const int kk = (lane < KC) ? lane : (KC - 1);   // clamped k index for k-lane phases

    float sumA2 = 0.f, entL = 0.f, sumSSt2 = 0.f, sumASSt = 0.f, l0 = 0.f, l1 = 0.f;

    // ---- P0: stage edges (packed local cells), x tile; zero agg/PT/ApBuf ----
    for (int e = tid; e < EPG; e += NTH) {
        int s = esrc[g * EPG + e] & (NP - 1);
        int d = edst[g * EPG + e] & (NP - 1);
        cells[e] = (unsigned short)((s << 8) | d);
    }
    for (int i = tid; i < NP * FIN; i += NTH) {
        u2f[i] = x[g * NP * FIN + i];   // x tile
        u2f[NP * FIN + i] = 0.f;        // agg
    }
    for (int i = tid; i < HD * KC; i += NTH) PT[i] = 0.f;
    for (int i = tid; i < KC * KC; i += NTH) ApBuf[i] = 0.f;
    __syncthreads();

    // ---- P1: sum(A^2) exactly. Two u16 counters packed per u32 word
    //      (max multiplicity 4096 < 65536 -> low half never carries) ----
    for (int ch = 0; ch < 2; ++ch) {
        for (int i = tid; i < 16384; i += NTH) u1.cnt[i] = 0u;
        __syncthreads();
        int base = ch << 15;
        for (int e = tid; e < EPG; e += NTH) {
            int r = (int)cells[e] - base;
            if ((unsigned)r < 32768u)
                atomicAdd(&u1.cnt[r >> 1], (r & 1) ? 0x10000u : 1u);
        }
        __syncthreads();
        for (int i = tid; i < 16384; i += NTH) {
            unsigned v = u1.cnt[i];
            float m0 = (float)(v & 0xffffu), m1 = (float)(v >> 16);
            sumA2 += m0 * m0 + m1 * m1;
        }
        __syncthreads();
    }

    // ---- P2: GIN aggregation: agg[di] += x[si] over edges ----
    for (int e = tid; e < EPG; e += NTH) {
        int c = cells[e]; int si = c >> 8, di = c & 255;
        #pragma unroll
        for (int f = 0; f < FIN; ++f)
            atomicAdd(&u2f[NP * FIN + di * FIN + f], u2f[si * FIN + f]);
    }
    __syncthreads();

    // ---- P3a: t1 = relu((x+agg) @ W1a + b1a)  -> u1.f[n*64+lane] ----
    {
        float w1r[FIN];
        #pragma unroll
        for (int f = 0; f < FIN; ++f) w1r[f] = W1a[f * HD + lane];
        float br = b1a[lane];
        for (int n = wid; n < NP; n += NWAVE) {
            float a = br;
            #pragma unroll
            for (int f = 0; f < FIN; ++f)
                a += (u2f[n * FIN + f] + u2f[NP * FIN + n * FIN + f]) * w1r[f];
            u1.f[n * HD + lane] = fmaxf(a, 0.f);
        }
    }
    __syncthreads();

    // ---- P3b: h = t1 @ W1b + b1b (in-place per row; rows private to a wave) ----
    {
        float wr[HD];
        #pragma unroll
        for (int j = 0; j < HD; ++j) wr[j] = W1b[j * HD + lane];
        float br = b1b[lane];
        for (int n = wid; n < NP; n += NWAVE) {
            float a0 = br, a1 = 0.f, a2 = 0.f, a3 = 0.f;
            const float4* t4 = (const float4*)&u1.f[n * HD];
            #pragma unroll
            for (int i = 0; i < 16; ++i) {
                float4 v = t4[i];
                a0 += v.x * wr[4*i]; a1 += v.y * wr[4*i+1];
                a2 += v.z * wr[4*i+2]; a3 += v.w * wr[4*i+3];
            }
            u1.f[n * HD + lane] = (a0 + a1) + (a2 + a3);
        }
    }
    __syncthreads();

    // ---- P4: S = softmax(h @ Wp + bp); entropy partial; S stride 52, pads=0 ----
    {
        float wr[HD];
        #pragma unroll
        for (int j = 0; j < HD; ++j) wr[j] = Wp[j * KC + kk];
        float br = bp[kk];
        for (int n = wid; n < NP; n += NWAVE) {
            float a0 = br, a1 = 0.f, a2 = 0.f, a3 = 0.f;
            const float4* h4 = (const float4*)&u1.f[n * HD];
            #pragma unroll
            for (int i = 0; i < 16; ++i) {
                float4 v = h4[i];
                a0 += v.x * wr[4*i]; a1 += v.y * wr[4*i+1];
                a2 += v.z * wr[4*i+2]; a3 += v.w * wr[4*i+3];
            }
            float a = (a0 + a1) + (a2 + a3);
            if (lane >= KC) a = -INFINITY;
            float m = a;
            #pragma unroll
            for (int o = 32; o > 0; o >>= 1) m = fmaxf(m, __shfl_xor(m, o));
            float e = expf(a - m);          // lanes >= KC -> 0
            float ss = e;
            #pragma unroll
            for (int o = 32; o > 0; o >>= 1) ss += __shfl_xor(ss, o);
            float s = e / ss;
            if (lane < SST) u2f[n * SST + lane] = s;   // pads (50,51) get 0
            if (lane < KC) entL += s * logf(s + 1e-15f);
        }
    }
    __syncthreads();

    // ---- P5: waves 0-7: xp = S^T h (reg-accumulated, atomic into PT)
    //          waves 8-15: G = S^T S (atomic into ApBuf) ----
    if (wid < 8) {
        float acc[HD];
        #pragma unroll
        for (int c = 0; c < HD; ++c) acc[c] = 0.f;
        int n0 = wid * 32;
        for (int n = n0; n < n0 + 32; ++n) {
            float sk = u2f[n * SST + kk];
            const float4* h4 = (const float4*)&u1.f[n * HD];
            #pragma unroll
            for (int i = 0; i < 16; ++i) {
                float4 v = h4[i];
                acc[4*i]   += sk * v.x; acc[4*i+1] += sk * v.y;
                acc[4*i+2] += sk * v.z; acc[4*i+3] += sk * v.w;
            }
        }
        if (lane < KC) {
            #pragma unroll
            for (int c = 0; c < HD; ++c) atomicAdd(&PT[c * KC + lane], acc[c]);
        }
    } else {
        float acc[SST];
        #pragma unroll
        for (int c = 0; c < SST; ++c) acc[c] = 0.f;
        int n0 = (wid - 8) * 32;
        for (int n = n0; n < n0 + 32; ++n) {
            float sk = u2f[n * SST + kk];
            const float4* s4 = (const float4*)&u2f[n * SST];
            #pragma unroll
            for (int i = 0; i < 13; ++i) {
                float4 v = s4[i];
                acc[4*i]   += sk * v.x; acc[4*i+1] += sk * v.y;
                acc[4*i+2] += sk * v.z; acc[4*i+3] += sk * v.w;
            }
        }
        if (lane < KC) {
            #pragma unroll
            for (int c = 0; c < KC; ++c) atomicAdd(&ApBuf[lane * KC + c], acc[c]);
        }
    }
    __syncthreads();

    // ---- P6a: sumSSt2 = ||G||_F^2 ; zero AS region (h is dead) ----
    for (int i = tid; i < KC * KC; i += NTH) { float v = ApBuf[i]; sumSSt2 += v * v; }
    for (int i = tid; i < NP * SST; i += NTH) u1.f[i] = 0.f;
    __syncthreads();

    // ---- P6b: zero ApBuf for Ap; AS scatter AS[si,:] += S[di,:] (lanes = k) ----
    for (int i = tid; i < KC * KC; i += NTH) ApBuf[i] = 0.f;
    for (int e = wid; e < EPG; e += NWAVE) {
        int c = cells[e]; int si = c >> 8, di = c & 255;
        float sv = u2f[di * SST + kk];
        if (lane < KC) atomicAdd(&u1.f[si * SST + lane], sv);
    }
    __syncthreads();

    // ---- P8: sumASSt = sum(AS .* S); Ap = S^T AS (atomic into ApBuf) ----
    {
        float ap[SST];
        #pragma unroll
        for (int c = 0; c < SST; ++c) ap[c] = 0.f;
        int n0 = wid * 16;
        for (int n = n0; n < n0 + 16; ++n) {
            float sk = u2f[n * SST + kk];
            if (lane < KC) sumASSt += sk * u1.f[n * SST + kk];
            const float4* a4 = (const float4*)&u1.f[n * SST];
            #pragma unroll
            for (int i = 0; i < 13; ++i) {
                float4 v = a4[i];
                ap[4*i]   += sk * v.x; ap[4*i+1] += sk * v.y;
                ap[4*i+2] += sk * v.z; ap[4*i+3] += sk * v.w;
            }
        }
        if (lane < KC) {
            #pragma unroll
            for (int c = 0; c < KC; ++c) atomicAdd(&ApBuf[lane * KC + c], ap[c]);
        }
    }
    __syncthreads();

    // ---- P9: h2 = xp + Ap @ xp  -> u2f[k*64+d] (S is dead) ----
    for (int k = wid; k < KC; k += NWAVE) {
        float a = PT[lane * KC + k];
        #pragma unroll
        for (int l = 0; l < KC; ++l)
            a += ApBuf[k * KC + l] * PT[lane * KC + l];
        u2f[k * HD + lane] = a;
    }
    __syncthreads();

    // ---- P10: t = relu(h2 @ W2a + b2a) -> u2f[KC*HD + ...] ----
    {
        float wr[HD];
        #pragma unroll
        for (int d = 0; d < HD; ++d) wr[d] = W2a[d * HD + lane];
        float br = b2a[lane];
        for (int k = wid; k < KC; k += NWAVE) {
            float a0 = br, a1 = 0.f, a2 = 0.f, a3 = 0.f;
            const float4* h4 = (const float4*)&u2f[k * HD];
            #pragma unroll
            for (int i = 0; i < 16; ++i) {
                float4 v = h4[i];
                a0 += v.x * wr[4*i]; a1 += v.y * wr[4*i+1];
                a2 += v.z * wr[4*i+2]; a3 += v.w * wr[4*i+3];
            }
            u2f[KC * HD + k * HD + lane] = fmaxf((a0 + a1) + (a2 + a3), 0.f);
        }
    }
    __syncthreads();

    // ---- P11: h3 = t @ W2b + b2b; fold mean over k and Wl into l0/l1 partials ----
    {
        float wr[HD];
        #pragma unroll
        for (int j = 0; j < HD; ++j) wr[j] = W2b[j * HD + lane];
        float br = b2b[lane];
        float wl0 = Wl[lane * 2], wl1 = Wl[lane * 2 + 1];
        for (int k = wid; k < KC; k += NWAVE) {
            float a0 = br, a1 = 0.f, a2 = 0.f, a3 = 0.f;
            const float4* t4 = (const float4*)&u2f[KC * HD + k * HD];
            #pragma unroll
            for (int i = 0; i < 16; ++i) {
                float4 v = t4[i];
                a0 += v.x * wr[4*i]; a1 += v.y * wr[4*i+1];
                a2 += v.z * wr[4*i+2]; a3 += v.w * wr[4*i+3];
            }
            float a = (a0 + a1) + (a2 + a3);
            l0 += a * wl0; l1 += a * wl1;
        }
    }

    // ---- P12: block reductions, loss atomics, per-graph log_softmax ----
    float rA2   = blockReduce(sumA2, red);
    float rASSt = blockReduce(sumASSt, red);
    float rSSt2 = blockReduce(sumSSt2, red);
    float rEnt  = blockReduce(entL, red);
    float rl0   = blockReduce(l0, red);
    float rl1   = blockReduce(l1, red);
    if (tid == 0) {
        atomicAdd(&ws[0], rA2 - 2.f * rASSt + rSSt2);
        atomicAdd(&ws[1], rEnt);
        float g0 = bl[0] + rl0 * (1.f / KC);
        float g1 = bl[1] + rl1 * (1.f / KC);
        float mm = fmaxf(g0, g1);
        float lse = mm + logf(expf(g0 - mm) + expf(g1 - mm));
        out[2 * g]     = g0 - lse;
        out[2 * g + 1] = g1 - lse;
    }
}

extern "C" void kernel_launch(void* const* d_in, const int* in_sizes, int n_in,
                              void* d_out, int out_size, void* d_ws, size_t ws_size,
                              hipStream_t stream) {
    const float* x    = (const float*)d_in[0];
    const float* W1a  = (const float*)d_in[1];
    const float* b1a  = (const float*)d_in[2];
    const float* W1b  = (const float*)d_in[3];
    const float* b1b  = (const float*)d_in[4];
    const float* Wp   = (const float*)d_in[5];
    const float* bp   = (const float*)d_in[6];
    const float* W2a  = (const float*)d_in[7];
    const float* b2a  = (const float*)d_in[8];
    const float* W2b  = (const float*)d_in[9];
    const float* b2b  = (const float*)d_in[10];
    const float* Wl   = (const float*)d_in[11];
    const float* bl   = (const float*)d_in[12];
    const int*   eidx = (const int*)d_in[13];   // [2, E] int32
    // d_in[14] (batch) unused: graphs are contiguous equal-size blocks
    float* out = (float*)d_out;
    float* ws  = (float*)d_ws;

    zero_ws<<<1, 64, 0, stream>>>(ws);
    graph_k<<<NG, NTH, 0, stream>>>(x, W1a, b1a, W1b, b1b, Wp, bp,
                                    W2a, b2a, W2b, b2b, Wl, bl,
                                    eidx, eidx + ETOT, out, ws);
    finalize_k<<<1, 64, 0, stream>>>(ws, out);
}

// Round 3
// 2342.995 us; speedup vs baseline: 1.4370x; 1.4370x over previous
//
#include <hip/hip_runtime.h>
#include <math.h>

// Problem constants (from reference)
#define NG   1024        // graphs
#define NP   256         // nodes per graph
#define EPG  4096        // edges per graph
#define ETOT 4194304     // total edges
#define NTOT (NG * NP)   // 262144 nodes
#define FIN  7
#define HD   64
#define KC   50
#define SST  52          // padded row stride for S / AS (16B-aligned rows, pads = 0)
#define CHK  64          // rows per K2 chunk
#define NCH  4           // chunks per graph

// NOTE (R2 post-mortem): __launch_bounds__ 2nd arg is CUDA-style min BLOCKS
// per CU. (1024,4) => 64 waves/CU => 64-VGPR cap => 5 GB of spill traffic.
// Keep caps such that VGPR budget >= 128 for the weight-in-register GEMMs.

// Inter-kernel intermediates as statics: no hipMalloc, graph-capture safe.
// Every element is rewritten each launch before being read.
__device__ unsigned short g_cells[ETOT];            // packed (si<<8)|di
__device__ float g_xagg[NTOT * 8];                  // x+agg, padded to 8
__device__ float g_S[NTOT * SST];                   // S rows, stride 52
__device__ float g_PTp[NG * NCH * HD * KC];         // xp partials [d][k]
__device__ float g_Gp[NG * NCH * KC * KC];          // G partials [k][c]
__device__ float g_Ap[NG * KC * KC];                // Ap [k][c]

__global__ void zero_ws(float* ws) {
    if (threadIdx.x < 4) ws[threadIdx.x] = 0.f;
}

// ws[0]=sumA2, ws[1]=sum S logS, ws[2]=sum AS.S, ws[3]=||G||^2
__global__ void finalize_k(const float* __restrict__ ws, float* __restrict__ out) {
    if (threadIdx.x == 0) {
        float num = ws[0] - 2.f * ws[2] + ws[3];
        float link = sqrtf(fmaxf(num, 0.f)) / 67108864.0f;   // / (B*n*n)
        float ent  = -ws[1] / 262144.0f;                     // / N
        out[2048] = link + ent;
    }
}

// generic block reduction; result valid on thread 0 only
__device__ __forceinline__ float blockReduceN(float v, float* red, int nw) {
    __syncthreads();   // protect red from previous use
    #pragma unroll
    for (int o = 32; o > 0; o >>= 1) v += __shfl_down(v, o);
    if ((threadIdx.x & 63) == 0) red[threadIdx.x >> 6] = v;
    __syncthreads();
    float r = 0.f;
    if (threadIdx.x == 0) {
        for (int i = 0; i < nw; ++i) r += red[i];
    }
    return r;
}

// ---------------- K1: edges -> cells, sum(A^2), GIN aggregation ----------------
// LDS ~54 KB -> 2 blocks/CU
__launch_bounds__(512, 2)
__global__ void k1_edges(const int* __restrict__ esrc, const int* __restrict__ edst,
                         const float* __restrict__ x, float* __restrict__ ws)
{
    __shared__ unsigned int cnt[8192];          // 32 KB (two u16 counters / word)
    __shared__ unsigned short cells[EPG];       // 8 KB
    __shared__ float xt[NP * FIN];              // 7 KB
    __shared__ float agg[NP * FIN];             // 7 KB
    __shared__ float red[8];

    const int g = blockIdx.x, tid = threadIdx.x;

    for (int e = tid; e < EPG; e += 512) {
        int s = esrc[g * EPG + e] & (NP - 1);
        int d = edst[g * EPG + e] & (NP - 1);
        cells[e] = (unsigned short)((s << 8) | d);
    }
    for (int i = tid; i < NP * FIN; i += 512) {
        xt[i]  = x[g * NP * FIN + i];
        agg[i] = 0.f;
    }
    __syncthreads();

    // persist cells for K3 (as u32 pairs, coalesced)
    for (int i = tid; i < EPG / 2; i += 512)
        ((unsigned int*)g_cells)[g * (EPG / 2) + i] = ((const unsigned int*)cells)[i];

    // sum(A^2): 4 chunks of 16384 cells, two u16 counters per u32 word
    float sumA2 = 0.f;
    for (int ch = 0; ch < 4; ++ch) {
        for (int i = tid; i < 8192; i += 512) cnt[i] = 0u;
        __syncthreads();
        int base = ch << 14;
        for (int e = tid; e < EPG; e += 512) {
            int r = (int)cells[e] - base;
            if ((unsigned)r < 16384u)
                atomicAdd(&cnt[r >> 1], (r & 1) ? 0x10000u : 1u);
        }
        __syncthreads();
        for (int i = tid; i < 8192; i += 512) {
            unsigned v = cnt[i];
            float m0 = (float)(v & 0xffffu), m1 = (float)(v >> 16);
            sumA2 += m0 * m0 + m1 * m1;
        }
        __syncthreads();
    }

    // GIN aggregation: agg[di] += x[si]
    for (int e = tid; e < EPG; e += 512) {
        int c = cells[e]; int si = c >> 8, di = c & 255;
        #pragma unroll
        for (int f = 0; f < FIN; ++f)
            atomicAdd(&agg[di * FIN + f], xt[si * FIN + f]);
    }
    __syncthreads();

    // write x+agg, padded to 8 floats/row
    for (int i = tid; i < NP * 8; i += 512) {
        int n = i >> 3, f = i & 7;
        float v = (f < FIN) ? (xt[n * FIN + f] + agg[n * FIN + f]) : 0.f;
        g_xagg[g * NP * 8 + i] = v;
    }

    float r = blockReduceN(sumA2, red, 8);
    if (tid == 0) atomicAdd(&ws[0], r);
}

// ---------------- K2: MLP1 + softmax S + xp/G partials (64-row chunks) --------
// LDS ~54.4 KB -> 2 blocks/CU
__launch_bounds__(512, 2)
__global__ void k2_mlp(const float* __restrict__ W1a, const float* __restrict__ b1a,
                       const float* __restrict__ W1b, const float* __restrict__ b1b,
                       const float* __restrict__ Wp,  const float* __restrict__ bp,
                       float* __restrict__ ws)
{
    __shared__ __align__(16) float xt[CHK * 8];        // 2 KB
    __shared__ __align__(16) float hrow[CHK * HD];     // 16 KB (t1 then h in-place)
    __shared__ __align__(16) float St[CHK * SST];      // 13.3 KB
    __shared__ __align__(16) float PT[HD * KC];        // 12.8 KB
    __shared__ __align__(16) float Gb[KC * KC];        // 10 KB
    __shared__ float red[8];

    const int b = blockIdx.x;
    const int rbase = b * CHK;                   // global row base (g*256 + c*64)
    const int tid = threadIdx.x;
    const int lane = tid & 63, wid = tid >> 6;
    const int kk = (lane < KC) ? lane : (KC - 1);

    float entL = 0.f;

    xt[tid] = g_xagg[rbase * 8 + tid];           // 512 = CHK*8 exactly
    for (int i = tid; i < HD * KC; i += 512) PT[i] = 0.f;
    for (int i = tid; i < KC * KC; i += 512) Gb[i] = 0.f;
    __syncthreads();

    // t1 = relu((x+agg) @ W1a + b1a)
    {
        float w1r[FIN];
        #pragma unroll
        for (int f = 0; f < FIN; ++f) w1r[f] = W1a[f * HD + lane];
        float br = b1a[lane];
        for (int n = wid; n < CHK; n += 8) {
            float a = br;
            #pragma unroll
            for (int f = 0; f < FIN; ++f) a += xt[n * 8 + f] * w1r[f];
            hrow[n * HD + lane] = fmaxf(a, 0.f);
        }
    }
    __syncthreads();

    // h = t1 @ W1b + b1b (rows private to a wave; in-place)
    {
        float wr[HD];
        #pragma unroll
        for (int j = 0; j < HD; ++j) wr[j] = W1b[j * HD + lane];
        float br = b1b[lane];
        for (int n = wid; n < CHK; n += 8) {
            float a0 = br, a1 = 0.f, a2 = 0.f, a3 = 0.f;
            const float4* t4 = (const float4*)&hrow[n * HD];
            #pragma unroll
            for (int i = 0; i < 16; ++i) {
                float4 v = t4[i];
                a0 += v.x * wr[4*i]; a1 += v.y * wr[4*i+1];
                a2 += v.z * wr[4*i+2]; a3 += v.w * wr[4*i+3];
            }
            hrow[n * HD + lane] = (a0 + a1) + (a2 + a3);
        }
    }
    __syncthreads();

    // S = softmax(h @ Wp + bp); entropy partial
    {
        float wr[HD];
        #pragma unroll
        for (int j = 0; j < HD; ++j) wr[j] = Wp[j * KC + kk];
        float br = bp[kk];
        for (int n = wid; n < CHK; n += 8) {
            float a0 = br, a1 = 0.f, a2 = 0.f, a3 = 0.f;
            const float4* h4 = (const float4*)&hrow[n * HD];
            #pragma unroll
            for (int i = 0; i < 16; ++i) {
                float4 v = h4[i];
                a0 += v.x * wr[4*i]; a1 += v.y * wr[4*i+1];
                a2 += v.z * wr[4*i+2]; a3 += v.w * wr[4*i+3];
            }
            float a = (a0 + a1) + (a2 + a3);
            if (lane >= KC) a = -INFINITY;
            float m = a;
            #pragma unroll
            for (int o = 32; o > 0; o >>= 1) m = fmaxf(m, __shfl_xor(m, o));
            float e = expf(a - m);
            float ss = e;
            #pragma unroll
            for (int o = 32; o > 0; o >>= 1) ss += __shfl_xor(ss, o);
            float s = e / ss;
            if (lane < SST) St[n * SST + lane] = s;    // pads (50,51) = 0
            if (lane < KC) entL += s * logf(s + 1e-15f);
        }
    }
    __syncthreads();

    // persist S rows (coalesced float4)
    for (int i = tid; i < CHK * SST / 4; i += 512)
        ((float4*)g_S)[rbase * (SST / 4) + i] = ((const float4*)St)[i];

    // xp partial (waves 0-3) and G partial (waves 4-7)
    if (wid < 4) {
        float acc[HD];
        #pragma unroll
        for (int c = 0; c < HD; ++c) acc[c] = 0.f;
        int n0 = wid * 16;
        for (int n = n0; n < n0 + 16; ++n) {
            float sk = St[n * SST + kk];
            const float4* h4 = (const float4*)&hrow[n * HD];
            #pragma unroll
            for (int i = 0; i < 16; ++i) {
                float4 v = h4[i];
                acc[4*i]   += sk * v.x; acc[4*i+1] += sk * v.y;
                acc[4*i+2] += sk * v.z; acc[4*i+3] += sk * v.w;
            }
        }
        if (lane < KC) {
            #pragma unroll
            for (int c = 0; c < HD; ++c) atomicAdd(&PT[c * KC + lane], acc[c]);
        }
    } else {
        float acc[SST];
        #pragma unroll
        for (int c = 0; c < SST; ++c) acc[c] = 0.f;
        int n0 = (wid - 4) * 16;
        for (int n = n0; n < n0 + 16; ++n) {
            float sk = St[n * SST + kk];
            const float4* s4 = (const float4*)&St[n * SST];
            #pragma unroll
            for (int i = 0; i < 13; ++i) {
                float4 v = s4[i];
                acc[4*i]   += sk * v.x; acc[4*i+1] += sk * v.y;
                acc[4*i+2] += sk * v.z; acc[4*i+3] += sk * v.w;
            }
        }
        if (lane < KC) {
            #pragma unroll
            for (int c = 0; c < KC; ++c) atomicAdd(&Gb[lane * KC + c], acc[c]);
        }
    }
    __syncthreads();

    // write partial slots (indexed by blockIdx = g*4+c)
    for (int i = tid; i < HD * KC; i += 512) g_PTp[b * HD * KC + i] = PT[i];
    for (int i = tid; i < KC * KC; i += 512) g_Gp[b * KC * KC + i] = Gb[i];

    float r = blockReduceN(entL, red, 8);
    if (tid == 0) atomicAdd(&ws[1], r);
}

// ---------------- K3: AS scatter + Ap = S^T AS + sum(AS.S) --------------------
// LDS ~124.6 KB -> 1 block/CU (isolated; measure it)
__launch_bounds__(512, 1)
__global__ void k3_as(float* __restrict__ ws)
{
    __shared__ __align__(16) float St[NP * SST];      // 53.2 KB
    __shared__ __align__(16) float AS[NP * SST];      // 53.2 KB
    __shared__ __align__(16) float Apb[KC * KC];      // 10 KB
    __shared__ unsigned short cells[EPG];             // 8 KB
    __shared__ float red[8];

    const int g = blockIdx.x, tid = threadIdx.x;
    const int lane = tid & 63, wid = tid >> 6;
    const int kk = (lane < KC) ? lane : (KC - 1);

    for (int i = tid; i < NP * SST / 4; i += 512) {
        ((float4*)St)[i] = ((const float4*)g_S)[g * NP * (SST / 4) + i];
        float4 z; z.x = z.y = z.z = z.w = 0.f;
        ((float4*)AS)[i] = z;
    }
    for (int i = tid; i < EPG / 2; i += 512)
        ((unsigned int*)cells)[i] = ((const unsigned int*)g_cells)[g * (EPG / 2) + i];
    for (int i = tid; i < KC * KC; i += 512) Apb[i] = 0.f;
    __syncthreads();

    // scatter AS[si,:] += S[di,:]  (lanes = k; 4-edge unroll for latency)
    {
        int e0 = wid * 512;
        for (int e = e0; e < e0 + 512; e += 4) {
            int c0 = cells[e], c1 = cells[e+1], c2 = cells[e+2], c3 = cells[e+3];
            float s0 = St[(c0 & 255) * SST + kk];
            float s1 = St[(c1 & 255) * SST + kk];
            float s2 = St[(c2 & 255) * SST + kk];
            float s3 = St[(c3 & 255) * SST + kk];
            if (lane < KC) {
                atomicAdd(&AS[(c0 >> 8) * SST + lane], s0);
                atomicAdd(&AS[(c1 >> 8) * SST + lane], s1);
                atomicAdd(&AS[(c2 >> 8) * SST + lane], s2);
                atomicAdd(&AS[(c3 >> 8) * SST + lane], s3);
            }
        }
    }
    __syncthreads();

    // Ap = S^T AS ; sumASSt = sum(AS .* S)
    float sumASSt = 0.f;
    {
        float ap[SST];
        #pragma unroll
        for (int c = 0; c < SST; ++c) ap[c] = 0.f;
        int n0 = wid * 32;
        for (int n = n0; n < n0 + 32; ++n) {
            float sk = St[n * SST + kk];
            if (lane < KC) sumASSt += sk * AS[n * SST + kk];
            const float4* a4 = (const float4*)&AS[n * SST];
            #pragma unroll
            for (int i = 0; i < 13; ++i) {
                float4 v = a4[i];
                ap[4*i]   += sk * v.x; ap[4*i+1] += sk * v.y;
                ap[4*i+2] += sk * v.z; ap[4*i+3] += sk * v.w;
            }
        }
        if (lane < KC) {
            #pragma unroll
            for (int c = 0; c < KC; ++c) atomicAdd(&Apb[lane * KC + c], ap[c]);
        }
    }
    __syncthreads();

    for (int i = tid; i < KC * KC; i += 512) g_Ap[g * KC * KC + i] = Apb[i];

    float r = blockReduceN(sumASSt, red, 8);
    if (tid == 0) atomicAdd(&ws[2], r);
}

// ---------------- K4: combine partials, ||G||^2, dense GIN, classifier -------
// LDS ~48.4 KB -> 3 blocks/CU
__launch_bounds__(256, 3)
__global__ void k4_head(const float* __restrict__ W2a, const float* __restrict__ b2a,
                        const float* __restrict__ W2b, const float* __restrict__ b2b,
                        const float* __restrict__ Wl,  const float* __restrict__ bl,
                        float* __restrict__ out, float* __restrict__ ws)
{
    __shared__ __align__(16) float PT[HD * KC];     // 12.8 KB
    __shared__ __align__(16) float Ap[KC * KC];     // 10 KB
    __shared__ __align__(16) float h2[KC * HD];     // 12.8 KB
    __shared__ __align__(16) float tt[KC * HD];     // 12.8 KB
    __shared__ float red[4];

    const int g = blockIdx.x, tid = threadIdx.x;
    const int lane = tid & 63, wid = tid >> 6;

    // sum xp partials
    for (int i = tid; i < HD * KC; i += 256) {
        float v = 0.f;
        #pragma unroll
        for (int c = 0; c < NCH; ++c) v += g_PTp[(g * NCH + c) * HD * KC + i];
        PT[i] = v;
    }
    // ||G||^2 partial (sum chunk partials first, then square)
    float sumG2 = 0.f;
    for (int i = tid; i < KC * KC; i += 256) {
        float v = 0.f;
        #pragma unroll
        for (int c = 0; c < NCH; ++c) v += g_Gp[(g * NCH + c) * KC * KC + i];
        sumG2 += v * v;
        Ap[i] = g_Ap[g * KC * KC + i];
    }
    __syncthreads();

    // h2 = xp + Ap @ xp   (PT[d][k] = xp[k][d])
    for (int k = wid; k < KC; k += 4) {
        float a = PT[lane * KC + k];
        #pragma unroll
        for (int l = 0; l < KC; ++l)
            a += Ap[k * KC + l] * PT[lane * KC + l];
        h2[k * HD + lane] = a;
    }
    __syncthreads();

    // t = relu(h2 @ W2a + b2a)
    {
        float wr[HD];
        #pragma unroll
        for (int d = 0; d < HD; ++d) wr[d] = W2a[d * HD + lane];
        float br = b2a[lane];
        for (int k = wid; k < KC; k += 4) {
            float a0 = br, a1 = 0.f, a2 = 0.f, a3 = 0.f;
            const float4* h4 = (const float4*)&h2[k * HD];
            #pragma unroll
            for (int i = 0; i < 16; ++i) {
                float4 v = h4[i];
                a0 += v.x * wr[4*i]; a1 += v.y * wr[4*i+1];
                a2 += v.z * wr[4*i+2]; a3 += v.w * wr[4*i+3];
            }
            tt[k * HD + lane] = fmaxf((a0 + a1) + (a2 + a3), 0.f);
        }
    }
    __syncthreads();

    // h3 = t @ W2b + b2b; fold mean over k and Wl into logits partials
    float l0 = 0.f, l1 = 0.f;
    {
        float wr[HD];
        #pragma unroll
        for (int j = 0; j < HD; ++j) wr[j] = W2b[j * HD + lane];
        float br = b2b[lane];
        float wl0 = Wl[lane * 2], wl1 = Wl[lane * 2 + 1];
        for (int k = wid; k < KC; k += 4) {
            float a0 = br, a1 = 0.f, a2 = 0.f, a3 = 0.f;
            const float4* t4 = (const float4*)&tt[k * HD];
            #pragma unroll
            for (int i = 0; i < 16; ++i) {
                float4 v = t4[i];
                a0 += v.x * wr[4*i]; a1 += v.y * wr[4*i+1];
                a2 += v.z * wr[4*i+2]; a3 += v.w * wr[4*i+3];
            }
            float a = (a0 + a1) + (a2 + a3);
            l0 += a * wl0; l1 += a * wl1;
        }
    }

    float rG2 = blockReduceN(sumG2, red, 4);
    float rl0 = blockReduceN(l0, red, 4);
    float rl1 = blockReduceN(l1, red, 4);
    if (tid == 0) {
        atomicAdd(&ws[3], rG2);
        float g0 = bl[0] + rl0 * (1.f / KC);
        float g1 = bl[1] + rl1 * (1.f / KC);
        float mm = fmaxf(g0, g1);
        float lse = mm + logf(expf(g0 - mm) + expf(g1 - mm));
        out[2 * g]     = g0 - lse;
        out[2 * g + 1] = g1 - lse;
    }
}

extern "C" void kernel_launch(void* const* d_in, const int* in_sizes, int n_in,
                              void* d_out, int out_size, void* d_ws, size_t ws_size,
                              hipStream_t stream) {
    const float* x    = (const float*)d_in[0];
    const float* W1a  = (const float*)d_in[1];
    const float* b1a  = (const float*)d_in[2];
    const float* W1b  = (const float*)d_in[3];
    const float* b1b  = (const float*)d_in[4];
    const float* Wp   = (const float*)d_in[5];
    const float* bp   = (const float*)d_in[6];
    const float* W2a  = (const float*)d_in[7];
    const float* b2a  = (const float*)d_in[8];
    const float* W2b  = (const float*)d_in[9];
    const float* b2b  = (const float*)d_in[10];
    const float* Wl   = (const float*)d_in[11];
    const float* bl   = (const float*)d_in[12];
    const int*   eidx = (const int*)d_in[13];   // [2, E] int32
    float* out = (float*)d_out;
    float* ws  = (float*)d_ws;

    zero_ws<<<1, 64, 0, stream>>>(ws);
    k1_edges<<<NG, 512, 0, stream>>>(eidx, eidx + ETOT, x, ws);
    k2_mlp<<<NG * NCH, 512, 0, stream>>>(W1a, b1a, W1b, b1b, Wp, bp, ws);
    k3_as<<<NG, 512, 0, stream>>>(ws);
    k4_head<<<NG, 256, 0, stream>>>(W2a, b2a, W2b, b2b, Wl, bl, out, ws);
    finalize_k<<<1, 64, 0, stream>>>(ws, out);
}